// Round 8
// baseline (585.210 us; speedup 1.0000x reference)
//
#include <hip/hip_runtime.h>
#include <hip/hip_bf16.h>

// Network_70918499991665: 12-layer implicit-map extractor, fwd + analytic grad.
// Round 7: (a) B/weights bypass LDS (direct global->reg, L1/L2-resident) halving
// LDS traffic; (b) 3-buffer A rotation -> ONE barrier per K-step, counted vmcnt;
// (c) fixed A-swizzle chunk ^= (row>>1)&3 (2-way, free; was 4-way).

#define NPTS 4096

typedef unsigned short u16;
typedef unsigned int   u32;
typedef __attribute__((ext_vector_type(8))) __bf16 bf16x8;
typedef __attribute__((ext_vector_type(4))) float  f32x4;

#define GLD_LDS16(g, l) __builtin_amdgcn_global_load_lds(                  \
    (const __attribute__((address_space(1))) void*)(g),                   \
    (__attribute__((address_space(3))) void*)(l), 16, 0, 0)

__device__ __forceinline__ float bf2f(u16 h) {
  return __uint_as_float(((u32)h) << 16);
}
__device__ __forceinline__ u16 f2bf(float f) {
  u32 u = __float_as_uint(f);
  u += 0x7fff + ((u >> 16) & 1);   // RNE
  return (u16)(u >> 16);
}

// softplus(100x)/100 and sigmoid(100x), numerically stable
__device__ __forceinline__ void act_sp_sg(float pre, float& sp, float& sg) {
  float z = 100.f * pre;
  float e = __expf(-fabsf(z));
  float r = 1.f / (1.f + e);
  float l = __logf(1.f + e) * 0.01f;
  if (z >= 0.f) { sg = r;       sp = pre + l; }
  else          { sg = 1.f - r; sp = l; }
}

// ---------------- weight norm: w[o] = g[o]*v[o]/||v[o]||, store bf16, pad zeros
struct LayerDesc { const float* v; const float* g; int Cin, Kpad, Cout, Mpad, woff; };
struct AllDesc { LayerDesc d[12]; };

__global__ __launch_bounds__(256)
void wnorm_kernel(AllDesc ad, u16* __restrict__ Wall) {
  const LayerDesc L = ad.d[blockIdx.y];
  const int o = blockIdx.x;
  if (o >= L.Mpad) return;
  u16* wrow = Wall + (size_t)L.woff + (size_t)o * L.Kpad;
  const int t = threadIdx.x;
  if (o >= L.Cout) {                       // zero pad rows
    for (int i = t; i < L.Kpad; i += 256) wrow[i] = 0;
    return;
  }
  const float* vrow = L.v + (size_t)o * L.Cin;
  float ss = 0.f;
  for (int i = t; i < L.Cin; i += 256) { float x = vrow[i]; ss += x * x; }
#pragma unroll
  for (int off = 32; off > 0; off >>= 1) ss += __shfl_down(ss, off);
  __shared__ float red[4];
  if ((t & 63) == 0) red[t >> 6] = ss;
  __syncthreads();
  const float scale = L.g[o] / sqrtf(red[0] + red[1] + red[2] + red[3]);
  for (int i = t; i < L.Kpad; i += 256)
    wrow[i] = (i < L.Cin) ? f2bf(vrow[i] * scale) : (u16)0;
}

// ---------------- build x0 [n][320] bf16 (pad 0) + input_con output (f32)
__global__ __launch_bounds__(256)
void build_x0(const float* __restrict__ inp, const float* __restrict__ lat,
              u16* __restrict__ x0, float* __restrict__ con) {
  const int n = blockIdx.x;
  for (int i = threadIdx.x; i < 320; i += 256) {
    float v = (i < 3) ? inp[n * 3 + i] : ((i < 259) ? lat[i - 3] : 0.f);
    x0[(size_t)n * 320 + i] = f2bf(v);
    if (i < 259) con[(size_t)n * 259 + i] = v;
  }
}

// bijective XCD swizzle (grid % 8 == 0 by construction), m-major chunks
__device__ __forceinline__ void xcd_decode(int nb, int ny, int& bx, int& by) {
  const int q = nb >> 3;
  const int wg = (blockIdx.x & 7) * q + (blockIdx.x >> 3);
  bx = wg / ny;
  by = wg - bx * ny;
}

// ---------------- fused MFMA layer, 128x128 tile, BK=32, 4 waves.
// A (activations): 3-buffer LDS rotation via global_load_lds, one barrier/K-step.
// B (weights): direct global->VGPR, L1/L2-resident, prefetched one step ahead.
// A-tile LDS: LINEAR [128 rows][32 u16]; slot (row, c) holds global k-chunk
// c ^ ((row>>1)&3); inverse permutation applied on per-lane GLOBAL address.
template<bool FIRST>
__global__ __launch_bounds__(256, 3)
void layer_mfma(const u16* __restrict__ W, const float* __restrict__ bias,
                const u16* __restrict__ Xin, u16* __restrict__ Xout,
                int Kpad, int Cout, int Cstr, int ny) {
  __shared__ __align__(16) u16 smem[18432];   // 36,864 B; loop uses 24 KB (3x8KB)
  const int t = threadIdx.x;
  const int wid = t >> 6, lane = t & 63;
  const int wr = wid >> 1, wc = wid & 1;
  const int lcol = lane & 15;
  const int hi = lane >> 4;                   // k-chunk 0..3 (8 bf16 each)
  const int lrow4 = hi * 4;

  int bx, by;
  xcd_decode(gridDim.x, ny, bx, by);
  const int n0 = bx * (FIRST ? 128 : 32);
  const int m0 = by * 128;

  f32x4 acc[4][4];
#pragma unroll
  for (int m = 0; m < 4; ++m)
#pragma unroll
    for (int n = 0; n < 4; ++n) acc[m][n] = (f32x4){0.f, 0.f, 0.f, 0.f};

  // A staging: wave stages rows wid*32..+31, 2 instrs of 16 rows each.
  // lane -> row = lane>>2 (within 16-row group), slot = lane&3;
  // global chunk fetched = (lane&3) ^ ((row>>1)&3)   [inverse swizzle]
  const int ldiv = lane >> 2;
  const int kswz = ((lane & 3) ^ ((ldiv >> 1) & 3)) * 8;   // u16 units
  const u16* gA = FIRST
      ? Xin + (size_t)(n0 + wid * 32 + ldiv) * Kpad + kswz
      : Xin + ((size_t)wid * NPTS + n0 + ldiv) * Kpad + kswz;

  auto stage = [&](int ks, int bufu16) {
    const int k0 = ks << 5;
#pragma unroll
    for (int i = 0; i < 2; ++i)
      GLD_LDS16(gA + (size_t)i * 16 * Kpad + k0,
                smem + bufu16 + (wid * 32 + i * 16) * 32);
  };

  bf16x8 bq[4], bqn[4];
  auto loadB = [&](int ks, bf16x8* dst) {
    const int k0 = ks << 5;
#pragma unroll
    for (int n = 0; n < 4; ++n) {
      const int row = wc * 64 + n * 16 + lcol;
      dst[n] = *reinterpret_cast<const bf16x8*>(
          W + (size_t)(m0 + row) * Kpad + k0 + hi * 8);
    }
  };

  const int ksteps = Kpad >> 5;              // >= 10 for all layers
  stage(0, 0);
  stage(1, 4096);
  loadB(0, bq);
  int sA = 0, sB = 4096, sC = 8192;
  for (int ks = 0; ks < ksteps; ++ks) {
    if (ks + 1 < ksteps) {
      asm volatile("s_waitcnt vmcnt(6)" ::: "memory");   // stage(ks) landed;
    } else {                                             // stage(ks+1)+loadB in flight
      asm volatile("s_waitcnt vmcnt(4)" ::: "memory");
    }
    __builtin_amdgcn_s_barrier();
    if (ks + 2 < ksteps) stage(ks + 2, sC);              // overwrite (ks-1)'s buffer
    if (ks + 1 < ksteps) loadB(ks + 1, bqn);
    const u16* As = smem + sA;
    bf16x8 af[4];
#pragma unroll
    for (int m = 0; m < 4; ++m) {
      const int row = wr * 64 + m * 16 + lcol;
      af[m] = *reinterpret_cast<const bf16x8*>(
          &As[row * 32 + ((hi ^ ((row >> 1) & 3)) * 8)]);
    }
#pragma unroll
    for (int m = 0; m < 4; ++m)
#pragma unroll
      for (int n = 0; n < 4; ++n)
        acc[m][n] = __builtin_amdgcn_mfma_f32_16x16x32_bf16(af[m], bq[n], acc[m][n], 0, 0, 0);
#pragma unroll
    for (int n = 0; n < 4; ++n) bq[n] = bqn[n];
    const int tmp = sA; sA = sB; sB = sC; sC = tmp;
  }
  __syncthreads();    // all waves done reading A-buffers; smem free for epilogue

  if constexpr (!FIRST) {
    u16* tile = smem;                 // [64][144] u16 (18,432 B)
    u16* sgL  = smem + 64 * 144;      // [32][136] bf16 (8,704 B)

    if (wr == 0) {     // stream-0 rows (0..31): sg -> LDS(bf16), acc -> softplus
#pragma unroll
      for (int m = 0; m < 2; ++m)
#pragma unroll
        for (int n = 0; n < 4; ++n) {
          const int colL = wc * 64 + n * 16 + lcol;
          const int col = m0 + colL;
          const float bcol = (col < Cout) ? bias[col] : 0.f;
#pragma unroll
          for (int i = 0; i < 4; ++i) {
            const int p = m * 16 + lrow4 + i;
            float sp = 0.f, sg = 0.f;
            if (col < Cout) act_sp_sg(acc[m][n][i] + bcol, sp, sg);
            sgL[p * 136 + colL] = f2bf(sg);
            acc[m][n][i] = sp;
          }
        }
    }
    __syncthreads();

    auto store_half = [&](int sbase) {
#pragma unroll
      for (int j = 0; j < 4; ++j) {
        const int c = j * 256 + t;
        const int row = c >> 4, colc = c & 15;
        const int colg = m0 + colc * 8;
        if (colg < Cstr) {
          const int s = sbase + (row >> 5), p = row & 31;
          *reinterpret_cast<uint4*>(
              &Xout[((size_t)s * NPTS + n0 + p) * Cstr + colg]) =
              *reinterpret_cast<const uint4*>(&tile[row * 144 + colc * 8]);
        }
      }
    };

    // half A: rows 0..63 = streams 0,1 (owned by wr==0 waves)
    if (wr == 0) {
#pragma unroll
      for (int m = 0; m < 4; ++m)
#pragma unroll
        for (int n = 0; n < 4; ++n) {
          const int colL = wc * 64 + n * 16 + lcol;
#pragma unroll
          for (int i = 0; i < 4; ++i) {
            const int row = m * 16 + lrow4 + i;   // 0..63
            const float v = (row < 32) ? acc[m][n][i]
                                       : bf2f(sgL[(row & 31) * 136 + colL]) * acc[m][n][i];
            tile[row * 144 + colL] = f2bf(v);
          }
        }
    }
    __syncthreads();
    store_half(0);
    __syncthreads();
    // half B: rows 64..127 = streams 2,3 (owned by wr==1 waves)
    if (wr == 1) {
#pragma unroll
      for (int m = 0; m < 4; ++m)
#pragma unroll
        for (int n = 0; n < 4; ++n) {
          const int colL = wc * 64 + n * 16 + lcol;
#pragma unroll
          for (int i = 0; i < 4; ++i) {
            const int row = m * 16 + lrow4 + i;   // tile row 0..63
            const float v = bf2f(sgL[(row & 31) * 136 + colL]) * acc[m][n][i];
            tile[row * 144 + colL] = f2bf(v);
          }
        }
    }
    __syncthreads();
    store_half(2);
  } else {
    u16* tile = smem;                 // [128][144] u16 = 36,864 B
    float w0r[4], w1r[4], w2r[4], bcolr[4];
#pragma unroll
    for (int n = 0; n < 4; ++n) {
      const int col = m0 + wc * 64 + n * 16 + lcol;
      float b = 0.f, w0 = 0.f, w1 = 0.f, w2 = 0.f;
      if (col < Cout) {
        b  = bias[col];
        w0 = bf2f(W[(size_t)col * Kpad + 0]);
        w1 = bf2f(W[(size_t)col * Kpad + 1]);
        w2 = bf2f(W[(size_t)col * Kpad + 2]);
      }
      bcolr[n] = b; w0r[n] = w0; w1r[n] = w1; w2r[n] = w2;
    }
#pragma unroll
    for (int s = 0; s < 4; ++s) {
      if (s > 0) __syncthreads();
#pragma unroll
      for (int m = 0; m < 4; ++m)
#pragma unroll
        for (int n = 0; n < 4; ++n) {
          const int colL = wc * 64 + n * 16 + lcol;
          const bool ok = (m0 + colL) < Cout;
#pragma unroll
          for (int i = 0; i < 4; ++i) {
            const int row = wr * 64 + m * 16 + lrow4 + i;
            float v = 0.f;
            if (ok) {
              float sp, sg;
              act_sp_sg(acc[m][n][i] + bcolr[n], sp, sg);
              v = (s == 0) ? sp
                : (s == 1) ? sg * w0r[n]
                : (s == 2) ? sg * w1r[n]
                           : sg * w2r[n];
            }
            tile[row * 144 + colL] = f2bf(v);
          }
        }
      __syncthreads();
#pragma unroll
      for (int j = 0; j < 8; ++j) {
        const int c = j * 256 + t;
        const int row = c >> 4, colc = c & 15;
        const int colg = m0 + colc * 8;
        if (colg < Cstr) {
          *reinterpret_cast<uint4*>(
              &Xout[((size_t)s * NPTS + n0 + row) * Cstr + colg]) =
              *reinterpret_cast<const uint4*>(&tile[row * 144 + colc * 8]);
        }
      }
    }
  }
}

// ---------------- final 1-channel layer: out + out_grad
__global__ __launch_bounds__(256)
void final_c10(const u16* __restrict__ W10, const float* __restrict__ b10,
               const u16* __restrict__ Xin, float* __restrict__ out,
               float* __restrict__ outg) {
  const int lane = threadIdx.x & 63;
  const int n = blockIdx.x * 4 + (threadIdx.x >> 6);
  float a0 = 0, a1 = 0, a2 = 0, a3 = 0;
  for (int i = lane; i < 896; i += 64) {
    const float w = bf2f(W10[i]);
    a0 += w * bf2f(Xin[((size_t)0 * NPTS + n) * 896 + i]);
    a1 += w * bf2f(Xin[((size_t)1 * NPTS + n) * 896 + i]);
    a2 += w * bf2f(Xin[((size_t)2 * NPTS + n) * 896 + i]);
    a3 += w * bf2f(Xin[((size_t)3 * NPTS + n) * 896 + i]);
  }
#pragma unroll
  for (int off = 32; off > 0; off >>= 1) {
    a0 += __shfl_xor(a0, off); a1 += __shfl_xor(a1, off);
    a2 += __shfl_xor(a2, off); a3 += __shfl_xor(a3, off);
  }
  if (lane == 0) {
    out[n] = a0 + b10[0];
    outg[n * 3 + 0] = a1; outg[n * 3 + 1] = a2; outg[n * 3 + 2] = a3;
  }
}

extern "C" void kernel_launch(void* const* d_in, const int* in_sizes, int n_in,
                              void* d_out, int out_size, void* d_ws, size_t ws_size,
                              hipStream_t stream) {
  // K padded to 32-mult; Cout padded to 128-mult (MPAD).
  static const int CIN [12] = {259,515,512,512,576,576,768,768,768,960,960,896};
  static const int KPAD[12] = {320,576,512,512,576,576,768,768,768,960,960,896};
  static const int COUT[12] = {515,512,512,576,576,768,768,768,960,960,896,1};
  static const int MPAD[12] = {640,512,512,640,640,768,768,768,1024,1024,896,1};

  size_t woff[13]; woff[0] = 0;
  for (int l = 0; l < 12; ++l) woff[l + 1] = woff[l] + (size_t)MPAD[l] * KPAD[l];

  char* ws = (char*)d_ws;
  u16* Wall = (u16*)ws;
  size_t off = (woff[12] * 2 + 255) & ~(size_t)255;
  u16* x0  = (u16*)(ws + off); off += (size_t)NPTS * 320 * 2;
  u16* XGA = (u16*)(ws + off); off += (size_t)4 * NPTS * 960 * 2;
  u16* XGB = (u16*)(ws + off);
  // total ws use ~77 MB

  float* out_sdf  = (float*)d_out;           // [4096]
  float* out_grad = out_sdf + NPTS;          // [4096][3]
  float* out_con  = out_sdf + NPTS + NPTS*3; // [4096][259]

  build_x0<<<dim3(NPTS), dim3(256), 0, stream>>>(
      (const float*)d_in[0], (const float*)d_in[1], x0, out_con);

  AllDesc ad;
  for (int l = 0; l < 12; ++l) {
    ad.d[l].v = (const float*)d_in[2 + 3 * l];
    ad.d[l].g = (const float*)d_in[3 + 3 * l];
    ad.d[l].Cin = CIN[l]; ad.d[l].Kpad = KPAD[l];
    ad.d[l].Cout = COUT[l]; ad.d[l].Mpad = MPAD[l];
    ad.d[l].woff = (int)woff[l];
  }
  wnorm_kernel<<<dim3(1024, 12), dim3(256), 0, stream>>>(ad, Wall);

  // layer 0 (first): x0 -> XGA (out stride = KPAD[1]); grid 32 x 5 = 160 blocks
  {
    const int ny = MPAD[0] / 128;
    layer_mfma<true><<<dim3((NPTS / 128) * ny), dim3(256), 0, stream>>>(
        Wall + woff[0], (const float*)d_in[4], x0, XGA, KPAD[0], COUT[0], KPAD[1], ny);
  }

  // layers 1..10: ping-pong; tile rows = 4 streams x 32 points
  u16* bufs[2] = {XGA, XGB};
  for (int l = 1; l <= 10; ++l) {
    u16* Xi = bufs[(l + 1) & 1];
    u16* Xo = bufs[l & 1];
    const int ny = MPAD[l] / 128;
    layer_mfma<false><<<dim3((NPTS / 32) * ny), dim3(256), 0, stream>>>(
        Wall + woff[l], (const float*)d_in[4 + 3 * l], Xi, Xo,
        KPAD[l], COUT[l], KPAD[l + 1], ny);
  }

  // final: layer 10 wrote XGA (stride 896)
  final_c10<<<dim3(NPTS / 4), dim3(256), 0, stream>>>(
      Wall + woff[11], (const float*)d_in[37], XGA, out_sdf, out_grad);
}

// Round 9
// 419.855 us; speedup vs baseline: 1.3938x; 1.3938x over previous
//
#include <hip/hip_runtime.h>
#include <hip/hip_bf16.h>

// Network_70918499991665: 12-layer implicit-map extractor, fwd + analytic grad.
// Round 8: B back to LDS (r7's global->reg B regressed: divergent wave-loads
// serialize the TA pipe). Keep r7's wins: (row>>1)&3 swizzle (647K conflicts),
// 3-buffer rotation with ONE barrier per K-step, counted vmcnt(4).
// 48KB LDS -> 3 blocks/CU.

#define NPTS 4096

typedef unsigned short u16;
typedef unsigned int   u32;
typedef __attribute__((ext_vector_type(8))) __bf16 bf16x8;
typedef __attribute__((ext_vector_type(4))) float  f32x4;

#define GLD_LDS16(g, l) __builtin_amdgcn_global_load_lds(                  \
    (const __attribute__((address_space(1))) void*)(g),                   \
    (__attribute__((address_space(3))) void*)(l), 16, 0, 0)

__device__ __forceinline__ float bf2f(u16 h) {
  return __uint_as_float(((u32)h) << 16);
}
__device__ __forceinline__ u16 f2bf(float f) {
  u32 u = __float_as_uint(f);
  u += 0x7fff + ((u >> 16) & 1);   // RNE
  return (u16)(u >> 16);
}

// softplus(100x)/100 and sigmoid(100x), numerically stable
__device__ __forceinline__ void act_sp_sg(float pre, float& sp, float& sg) {
  float z = 100.f * pre;
  float e = __expf(-fabsf(z));
  float r = 1.f / (1.f + e);
  float l = __logf(1.f + e) * 0.01f;
  if (z >= 0.f) { sg = r;       sp = pre + l; }
  else          { sg = 1.f - r; sp = l; }
}

// ---------------- weight norm: w[o] = g[o]*v[o]/||v[o]||, store bf16, pad zeros
struct LayerDesc { const float* v; const float* g; int Cin, Kpad, Cout, Mpad, woff; };
struct AllDesc { LayerDesc d[12]; };

__global__ __launch_bounds__(256)
void wnorm_kernel(AllDesc ad, u16* __restrict__ Wall) {
  const LayerDesc L = ad.d[blockIdx.y];
  const int o = blockIdx.x;
  if (o >= L.Mpad) return;
  u16* wrow = Wall + (size_t)L.woff + (size_t)o * L.Kpad;
  const int t = threadIdx.x;
  if (o >= L.Cout) {                       // zero pad rows
    for (int i = t; i < L.Kpad; i += 256) wrow[i] = 0;
    return;
  }
  const float* vrow = L.v + (size_t)o * L.Cin;
  float ss = 0.f;
  for (int i = t; i < L.Cin; i += 256) { float x = vrow[i]; ss += x * x; }
#pragma unroll
  for (int off = 32; off > 0; off >>= 1) ss += __shfl_down(ss, off);
  __shared__ float red[4];
  if ((t & 63) == 0) red[t >> 6] = ss;
  __syncthreads();
  const float scale = L.g[o] / sqrtf(red[0] + red[1] + red[2] + red[3]);
  for (int i = t; i < L.Kpad; i += 256)
    wrow[i] = (i < L.Cin) ? f2bf(vrow[i] * scale) : (u16)0;
}

// ---------------- build x0 [n][320] bf16 (pad 0) + input_con output (f32)
__global__ __launch_bounds__(256)
void build_x0(const float* __restrict__ inp, const float* __restrict__ lat,
              u16* __restrict__ x0, float* __restrict__ con) {
  const int n = blockIdx.x;
  for (int i = threadIdx.x; i < 320; i += 256) {
    float v = (i < 3) ? inp[n * 3 + i] : ((i < 259) ? lat[i - 3] : 0.f);
    x0[(size_t)n * 320 + i] = f2bf(v);
    if (i < 259) con[(size_t)n * 259 + i] = v;
  }
}

// bijective XCD swizzle (grid % 8 == 0 by construction), m-major chunks
__device__ __forceinline__ void xcd_decode(int nb, int ny, int& bx, int& by) {
  const int q = nb >> 3;
  const int wg = (blockIdx.x & 7) * q + (blockIdx.x >> 3);
  bx = wg / ny;
  by = wg - bx * ny;
}

// ---------------- fused MFMA layer, 128x128 tile, BK=32, 4 waves.
// A and B staged via global_load_lds into 3 rotating 16KB buffers (A 8KB + B 8KB);
// ONE barrier per K-step, counted vmcnt(4). LDS slot (row, c) holds global
// k-chunk c ^ ((row>>1)&3); inverse permutation on the per-lane GLOBAL address.
template<bool FIRST>
__global__ __launch_bounds__(256, 3)
void layer_mfma(const u16* __restrict__ W, const float* __restrict__ bias,
                const u16* __restrict__ Xin, u16* __restrict__ Xout,
                int Kpad, int Cout, int Cstr, int ny) {
  __shared__ __align__(16) u16 smem[24576];   // 49,152 B: 3 x (A 8KB + B 8KB)
  const int t = threadIdx.x;
  const int wid = t >> 6, lane = t & 63;
  const int wr = wid >> 1, wc = wid & 1;
  const int lcol = lane & 15;
  const int hi = lane >> 4;                   // k-chunk 0..3 (8 bf16 each)
  const int lrow4 = hi * 4;

  int bx, by;
  xcd_decode(gridDim.x, ny, bx, by);
  const int n0 = bx * (FIRST ? 128 : 32);
  const int m0 = by * 128;

  f32x4 acc[4][4];
#pragma unroll
  for (int m = 0; m < 4; ++m)
#pragma unroll
    for (int n = 0; n < 4; ++n) acc[m][n] = (f32x4){0.f, 0.f, 0.f, 0.f};

  // staging: wave stages rows wid*32..+31 of A and B, 2 instrs of 16 rows each.
  // lane -> row = lane>>2 (in 16-row group), slot = lane&3;
  // global chunk fetched = (lane&3) ^ ((row>>1)&3)   [inverse swizzle]
  const int ldiv = lane >> 2;
  const int kswz = ((lane & 3) ^ ((ldiv >> 1) & 3)) * 8;   // u16 units
  const u16* gA = FIRST
      ? Xin + (size_t)(n0 + wid * 32 + ldiv) * Kpad + kswz
      : Xin + ((size_t)wid * NPTS + n0 + ldiv) * Kpad + kswz;
  const u16* gB = W + (size_t)(m0 + wid * 32 + ldiv) * Kpad + kswz;

  auto stage = [&](int ks, int bufu16) {
    const int k0 = ks << 5;
#pragma unroll
    for (int i = 0; i < 2; ++i) {
      GLD_LDS16(gA + (size_t)i * 16 * Kpad + k0,
                smem + bufu16 + (wid * 32 + i * 16) * 32);
      GLD_LDS16(gB + (size_t)i * 16 * Kpad + k0,
                smem + bufu16 + 4096 + (wid * 32 + i * 16) * 32);
    }
  };

  const int ksteps = Kpad >> 5;              // >= 10 for all layers
  stage(0, 0);
  stage(1, 8192);
  int sA = 0, sB = 8192, sC = 16384;
  for (int ks = 0; ks < ksteps; ++ks) {
    if (ks + 1 < ksteps) {
      asm volatile("s_waitcnt vmcnt(4)" ::: "memory");   // stage(ks) landed
    } else {
      asm volatile("s_waitcnt vmcnt(0)" ::: "memory");
    }
    __builtin_amdgcn_s_barrier();
    if (ks + 2 < ksteps) stage(ks + 2, sC);              // overwrite (ks-1) buffer
    const u16* As = smem + sA;
    const u16* Bs = As + 4096;
    bf16x8 af[4], bfr[4];
#pragma unroll
    for (int m = 0; m < 4; ++m) {
      const int row = wr * 64 + m * 16 + lcol;
      af[m] = *reinterpret_cast<const bf16x8*>(
          &As[row * 32 + ((hi ^ ((row >> 1) & 3)) * 8)]);
    }
#pragma unroll
    for (int n = 0; n < 4; ++n) {
      const int row = wc * 64 + n * 16 + lcol;
      bfr[n] = *reinterpret_cast<const bf16x8*>(
          &Bs[row * 32 + ((hi ^ ((row >> 1) & 3)) * 8)]);
    }
#pragma unroll
    for (int m = 0; m < 4; ++m)
#pragma unroll
      for (int n = 0; n < 4; ++n)
        acc[m][n] = __builtin_amdgcn_mfma_f32_16x16x32_bf16(af[m], bfr[n], acc[m][n], 0, 0, 0);
    const int tmp = sA; sA = sB; sB = sC; sC = tmp;
  }
  __syncthreads();    // all waves done with buffers; smem free for epilogue

  if constexpr (!FIRST) {
    u16* tile = smem;                 // [64][144] u16 (18,432 B)
    u16* sgL  = smem + 64 * 144;      // [32][136] bf16 (8,704 B)

    if (wr == 0) {     // stream-0 rows (0..31): sg -> LDS(bf16), acc -> softplus
#pragma unroll
      for (int m = 0; m < 2; ++m)
#pragma unroll
        for (int n = 0; n < 4; ++n) {
          const int colL = wc * 64 + n * 16 + lcol;
          const int col = m0 + colL;
          const float bcol = (col < Cout) ? bias[col] : 0.f;
#pragma unroll
          for (int i = 0; i < 4; ++i) {
            const int p = m * 16 + lrow4 + i;
            float sp = 0.f, sg = 0.f;
            if (col < Cout) act_sp_sg(acc[m][n][i] + bcol, sp, sg);
            sgL[p * 136 + colL] = f2bf(sg);
            acc[m][n][i] = sp;
          }
        }
    }
    __syncthreads();

    auto store_half = [&](int sbase) {
#pragma unroll
      for (int j = 0; j < 4; ++j) {
        const int c = j * 256 + t;
        const int row = c >> 4, colc = c & 15;
        const int colg = m0 + colc * 8;
        if (colg < Cstr) {
          const int s = sbase + (row >> 5), p = row & 31;
          *reinterpret_cast<uint4*>(
              &Xout[((size_t)s * NPTS + n0 + p) * Cstr + colg]) =
              *reinterpret_cast<const uint4*>(&tile[row * 144 + colc * 8]);
        }
      }
    };

    // half A: rows 0..63 = streams 0,1 (owned by wr==0 waves)
    if (wr == 0) {
#pragma unroll
      for (int m = 0; m < 4; ++m)
#pragma unroll
        for (int n = 0; n < 4; ++n) {
          const int colL = wc * 64 + n * 16 + lcol;
#pragma unroll
          for (int i = 0; i < 4; ++i) {
            const int row = m * 16 + lrow4 + i;   // 0..63
            const float v = (row < 32) ? acc[m][n][i]
                                       : bf2f(sgL[(row & 31) * 136 + colL]) * acc[m][n][i];
            tile[row * 144 + colL] = f2bf(v);
          }
        }
    }
    __syncthreads();
    store_half(0);
    __syncthreads();
    // half B: rows 64..127 = streams 2,3 (owned by wr==1 waves)
    if (wr == 1) {
#pragma unroll
      for (int m = 0; m < 4; ++m)
#pragma unroll
        for (int n = 0; n < 4; ++n) {
          const int colL = wc * 64 + n * 16 + lcol;
#pragma unroll
          for (int i = 0; i < 4; ++i) {
            const int row = m * 16 + lrow4 + i;   // tile row 0..63
            const float v = bf2f(sgL[(row & 31) * 136 + colL]) * acc[m][n][i];
            tile[row * 144 + colL] = f2bf(v);
          }
        }
    }
    __syncthreads();
    store_half(2);
  } else {
    u16* tile = smem;                 // [128][144] u16 = 36,864 B
    float w0r[4], w1r[4], w2r[4], bcolr[4];
#pragma unroll
    for (int n = 0; n < 4; ++n) {
      const int col = m0 + wc * 64 + n * 16 + lcol;
      float b = 0.f, w0 = 0.f, w1 = 0.f, w2 = 0.f;
      if (col < Cout) {
        b  = bias[col];
        w0 = bf2f(W[(size_t)col * Kpad + 0]);
        w1 = bf2f(W[(size_t)col * Kpad + 1]);
        w2 = bf2f(W[(size_t)col * Kpad + 2]);
      }
      bcolr[n] = b; w0r[n] = w0; w1r[n] = w1; w2r[n] = w2;
    }
#pragma unroll
    for (int s = 0; s < 4; ++s) {
      if (s > 0) __syncthreads();
#pragma unroll
      for (int m = 0; m < 4; ++m)
#pragma unroll
        for (int n = 0; n < 4; ++n) {
          const int colL = wc * 64 + n * 16 + lcol;
          const bool ok = (m0 + colL) < Cout;
#pragma unroll
          for (int i = 0; i < 4; ++i) {
            const int row = wr * 64 + m * 16 + lrow4 + i;
            float v = 0.f;
            if (ok) {
              float sp, sg;
              act_sp_sg(acc[m][n][i] + bcolr[n], sp, sg);
              v = (s == 0) ? sp
                : (s == 1) ? sg * w0r[n]
                : (s == 2) ? sg * w1r[n]
                           : sg * w2r[n];
            }
            tile[row * 144 + colL] = f2bf(v);
          }
        }
      __syncthreads();
#pragma unroll
      for (int j = 0; j < 8; ++j) {
        const int c = j * 256 + t;
        const int row = c >> 4, colc = c & 15;
        const int colg = m0 + colc * 8;
        if (colg < Cstr) {
          *reinterpret_cast<uint4*>(
              &Xout[((size_t)s * NPTS + n0 + row) * Cstr + colg]) =
              *reinterpret_cast<const uint4*>(&tile[row * 144 + colc * 8]);
        }
      }
    }
  }
}

// ---------------- final 1-channel layer: out + out_grad
__global__ __launch_bounds__(256)
void final_c10(const u16* __restrict__ W10, const float* __restrict__ b10,
               const u16* __restrict__ Xin, float* __restrict__ out,
               float* __restrict__ outg) {
  const int lane = threadIdx.x & 63;
  const int n = blockIdx.x * 4 + (threadIdx.x >> 6);
  float a0 = 0, a1 = 0, a2 = 0, a3 = 0;
  for (int i = lane; i < 896; i += 64) {
    const float w = bf2f(W10[i]);
    a0 += w * bf2f(Xin[((size_t)0 * NPTS + n) * 896 + i]);
    a1 += w * bf2f(Xin[((size_t)1 * NPTS + n) * 896 + i]);
    a2 += w * bf2f(Xin[((size_t)2 * NPTS + n) * 896 + i]);
    a3 += w * bf2f(Xin[((size_t)3 * NPTS + n) * 896 + i]);
  }
#pragma unroll
  for (int off = 32; off > 0; off >>= 1) {
    a0 += __shfl_xor(a0, off); a1 += __shfl_xor(a1, off);
    a2 += __shfl_xor(a2, off); a3 += __shfl_xor(a3, off);
  }
  if (lane == 0) {
    out[n] = a0 + b10[0];
    outg[n * 3 + 0] = a1; outg[n * 3 + 1] = a2; outg[n * 3 + 2] = a3;
  }
}

extern "C" void kernel_launch(void* const* d_in, const int* in_sizes, int n_in,
                              void* d_out, int out_size, void* d_ws, size_t ws_size,
                              hipStream_t stream) {
  // K padded to 32-mult; Cout padded to 128-mult (MPAD).
  static const int CIN [12] = {259,515,512,512,576,576,768,768,768,960,960,896};
  static const int KPAD[12] = {320,576,512,512,576,576,768,768,768,960,960,896};
  static const int COUT[12] = {515,512,512,576,576,768,768,768,960,960,896,1};
  static const int MPAD[12] = {640,512,512,640,640,768,768,768,1024,1024,896,1};

  size_t woff[13]; woff[0] = 0;
  for (int l = 0; l < 12; ++l) woff[l + 1] = woff[l] + (size_t)MPAD[l] * KPAD[l];

  char* ws = (char*)d_ws;
  u16* Wall = (u16*)ws;
  size_t off = (woff[12] * 2 + 255) & ~(size_t)255;
  u16* x0  = (u16*)(ws + off); off += (size_t)NPTS * 320 * 2;
  u16* XGA = (u16*)(ws + off); off += (size_t)4 * NPTS * 960 * 2;
  u16* XGB = (u16*)(ws + off);
  // total ws use ~77 MB

  float* out_sdf  = (float*)d_out;           // [4096]
  float* out_grad = out_sdf + NPTS;          // [4096][3]
  float* out_con  = out_sdf + NPTS + NPTS*3; // [4096][259]

  build_x0<<<dim3(NPTS), dim3(256), 0, stream>>>(
      (const float*)d_in[0], (const float*)d_in[1], x0, out_con);

  AllDesc ad;
  for (int l = 0; l < 12; ++l) {
    ad.d[l].v = (const float*)d_in[2 + 3 * l];
    ad.d[l].g = (const float*)d_in[3 + 3 * l];
    ad.d[l].Cin = CIN[l]; ad.d[l].Kpad = KPAD[l];
    ad.d[l].Cout = COUT[l]; ad.d[l].Mpad = MPAD[l];
    ad.d[l].woff = (int)woff[l];
  }
  wnorm_kernel<<<dim3(1024, 12), dim3(256), 0, stream>>>(ad, Wall);

  // layer 0 (first): x0 -> XGA (out stride = KPAD[1]); grid 32 x 5 = 160 blocks
  {
    const int ny = MPAD[0] / 128;
    layer_mfma<true><<<dim3((NPTS / 128) * ny), dim3(256), 0, stream>>>(
        Wall + woff[0], (const float*)d_in[4], x0, XGA, KPAD[0], COUT[0], KPAD[1], ny);
  }

  // layers 1..10: ping-pong; tile rows = 4 streams x 32 points
  u16* bufs[2] = {XGA, XGB};
  for (int l = 1; l <= 10; ++l) {
    u16* Xi = bufs[(l + 1) & 1];
    u16* Xo = bufs[l & 1];
    const int ny = MPAD[l] / 128;
    layer_mfma<false><<<dim3((NPTS / 32) * ny), dim3(256), 0, stream>>>(
        Wall + woff[l], (const float*)d_in[4 + 3 * l], Xi, Xo,
        KPAD[l], COUT[l], KPAD[l + 1], ny);
  }

  // final: layer 10 wrote XGA (stride 896)
  final_c10<<<dim3(NPTS / 4), dim3(256), 0, stream>>>(
      Wall + woff[11], (const float*)d_in[37], XGA, out_sdf, out_grad);
}

// Round 10
// 406.659 us; speedup vs baseline: 1.4391x; 1.0324x over previous
//
#include <hip/hip_runtime.h>
#include <hip/hip_bf16.h>

// Network_70918499991665: 12-layer implicit-map extractor, fwd + analytic grad.
// Round 9: compile-time KPAD/COUT/CSTR + fully unrolled K-loop. Kills the
// measured VALU address bloat (21.6% VALUBusy for 8 ds_read + 4 GLD/step):
// static 3-buffer rotation, immediate-offset ds_reads, GLD k-offset folded
// into 13-bit global offset. Structure otherwise identical to r8
// (BK=32, 3x16KB rotating buffers, one barrier/step, counted vmcnt(4)).

#define NPTS 4096

typedef unsigned short u16;
typedef unsigned int   u32;
typedef __attribute__((ext_vector_type(8))) __bf16 bf16x8;
typedef __attribute__((ext_vector_type(4))) float  f32x4;

#define GLD_LDS16(g, l) __builtin_amdgcn_global_load_lds(                  \
    (const __attribute__((address_space(1))) void*)(g),                   \
    (__attribute__((address_space(3))) void*)(l), 16, 0, 0)

__device__ __forceinline__ float bf2f(u16 h) {
  return __uint_as_float(((u32)h) << 16);
}
__device__ __forceinline__ u16 f2bf(float f) {
  u32 u = __float_as_uint(f);
  u += 0x7fff + ((u >> 16) & 1);   // RNE
  return (u16)(u >> 16);
}

// softplus(100x)/100 and sigmoid(100x), numerically stable
__device__ __forceinline__ void act_sp_sg(float pre, float& sp, float& sg) {
  float z = 100.f * pre;
  float e = __expf(-fabsf(z));
  float r = 1.f / (1.f + e);
  float l = __logf(1.f + e) * 0.01f;
  if (z >= 0.f) { sg = r;       sp = pre + l; }
  else          { sg = 1.f - r; sp = l; }
}

// ---------------- weight norm: w[o] = g[o]*v[o]/||v[o]||, store bf16, pad zeros
struct LayerDesc { const float* v; const float* g; int Cin, Kpad, Cout, Mpad, woff; };
struct AllDesc { LayerDesc d[12]; };

__global__ __launch_bounds__(256)
void wnorm_kernel(AllDesc ad, u16* __restrict__ Wall) {
  const LayerDesc L = ad.d[blockIdx.y];
  const int o = blockIdx.x;
  if (o >= L.Mpad) return;
  u16* wrow = Wall + (size_t)L.woff + (size_t)o * L.Kpad;
  const int t = threadIdx.x;
  if (o >= L.Cout) {                       // zero pad rows
    for (int i = t; i < L.Kpad; i += 256) wrow[i] = 0;
    return;
  }
  const float* vrow = L.v + (size_t)o * L.Cin;
  float ss = 0.f;
  for (int i = t; i < L.Cin; i += 256) { float x = vrow[i]; ss += x * x; }
#pragma unroll
  for (int off = 32; off > 0; off >>= 1) ss += __shfl_down(ss, off);
  __shared__ float red[4];
  if ((t & 63) == 0) red[t >> 6] = ss;
  __syncthreads();
  const float scale = L.g[o] / sqrtf(red[0] + red[1] + red[2] + red[3]);
  for (int i = t; i < L.Kpad; i += 256)
    wrow[i] = (i < L.Cin) ? f2bf(vrow[i] * scale) : (u16)0;
}

// ---------------- build x0 [n][320] bf16 (pad 0) + input_con output (f32)
__global__ __launch_bounds__(256)
void build_x0(const float* __restrict__ inp, const float* __restrict__ lat,
              u16* __restrict__ x0, float* __restrict__ con) {
  const int n = blockIdx.x;
  for (int i = threadIdx.x; i < 320; i += 256) {
    float v = (i < 3) ? inp[n * 3 + i] : ((i < 259) ? lat[i - 3] : 0.f);
    x0[(size_t)n * 320 + i] = f2bf(v);
    if (i < 259) con[(size_t)n * 259 + i] = v;
  }
}

// bijective XCD swizzle (grid % 8 == 0 by construction), m-major chunks
__device__ __forceinline__ void xcd_decode(int nb, int ny, int& bx, int& by) {
  const int q = nb >> 3;
  const int wg = (blockIdx.x & 7) * q + (blockIdx.x >> 3);
  bx = wg / ny;
  by = wg - bx * ny;
}

// ---------------- fused MFMA layer, 128x128 tile, BK=32, 4 waves.
// 3 rotating 16KB buffers (A 8KB + B 8KB), one barrier/step, counted vmcnt(4).
// LDS slot (row, c) holds global k-chunk c ^ ((row>>1)&3); inverse permutation
// on the per-lane GLOBAL address. KPAD/COUT/CSTR compile-time; K-loop fully
// unrolled -> static rotation + immediate-offset addressing.
template<bool FIRST, int KPAD, int COUT, int CSTR>
__global__ __launch_bounds__(256, 3)
void layer_mfma(const u16* __restrict__ W, const float* __restrict__ bias,
                const u16* __restrict__ Xin, u16* __restrict__ Xout, int ny) {
  constexpr int KSTEPS = KPAD / 32;
  __shared__ __align__(16) u16 smem[24576];   // 49,152 B: 3 x (A 8KB + B 8KB)
  const int t = threadIdx.x;
  const int wid = t >> 6, lane = t & 63;
  const int wr = wid >> 1, wc = wid & 1;
  const int lcol = lane & 15;
  const int hi = lane >> 4;                   // k-chunk 0..3 (8 bf16 each)
  const int lrow4 = hi * 4;

  int bx, by;
  xcd_decode(gridDim.x, ny, bx, by);
  const int n0 = bx * (FIRST ? 128 : 32);
  const int m0 = by * 128;

  f32x4 acc[4][4];
#pragma unroll
  for (int m = 0; m < 4; ++m)
#pragma unroll
    for (int n = 0; n < 4; ++n) acc[m][n] = (f32x4){0.f, 0.f, 0.f, 0.f};

  // staging: wave stages rows wid*32..+31 of A and B, 2 GLDs of 16 rows each.
  // lane -> row = lane>>2 (in 16-row group), slot = lane&3;
  // global chunk fetched = (lane&3) ^ ((row>>1)&3)   [inverse swizzle]
  const int ldiv = lane >> 2;
  const int kswz = ((lane & 3) ^ ((ldiv >> 1) & 3)) * 8;   // u16 units
  const u16* gA = FIRST
      ? Xin + (size_t)(n0 + wid * 32 + ldiv) * KPAD + kswz
      : Xin + ((size_t)wid * NPTS + n0 + ldiv) * KPAD + kswz;
  const u16* gB  = W + (size_t)(m0 + wid * 32 + ldiv) * KPAD + kswz;
  const u16* gA2 = gA + (size_t)16 * KPAD;
  const u16* gB2 = gB + (size_t)16 * KPAD;

  auto stage = [&](int ks, int bufu16) {     // ks, bufu16 compile-time (unrolled)
    const int k0 = ks << 5;                  // u16 units; bytes = 64*ks <= 1920
    GLD_LDS16(gA  + k0, smem + bufu16 + wid * 1024);
    GLD_LDS16(gA2 + k0, smem + bufu16 + wid * 1024 + 512);
    GLD_LDS16(gB  + k0, smem + bufu16 + 4096 + wid * 1024);
    GLD_LDS16(gB2 + k0, smem + bufu16 + 4096 + wid * 1024 + 512);
  };

  stage(0, 0);
  stage(1, 8192);
#pragma unroll
  for (int ks = 0; ks < KSTEPS; ++ks) {
    if (ks + 1 < KSTEPS) {
      asm volatile("s_waitcnt vmcnt(4)" ::: "memory");   // stage(ks) landed
    } else {
      asm volatile("s_waitcnt vmcnt(0)" ::: "memory");
    }
    __builtin_amdgcn_s_barrier();
    if (ks + 2 < KSTEPS) stage(ks + 2, ((ks + 2) % 3) * 8192);
    const u16* As = smem + (ks % 3) * 8192;  // static with full unroll
    const u16* Bs = As + 4096;
    bf16x8 af[4], bfr[4];
#pragma unroll
    for (int m = 0; m < 4; ++m) {
      const int row = wr * 64 + m * 16 + lcol;
      af[m] = *reinterpret_cast<const bf16x8*>(
          &As[row * 32 + ((hi ^ ((row >> 1) & 3)) * 8)]);
    }
#pragma unroll
    for (int n = 0; n < 4; ++n) {
      const int row = wc * 64 + n * 16 + lcol;
      bfr[n] = *reinterpret_cast<const bf16x8*>(
          &Bs[row * 32 + ((hi ^ ((row >> 1) & 3)) * 8)]);
    }
#pragma unroll
    for (int m = 0; m < 4; ++m)
#pragma unroll
      for (int n = 0; n < 4; ++n)
        acc[m][n] = __builtin_amdgcn_mfma_f32_16x16x32_bf16(af[m], bfr[n], acc[m][n], 0, 0, 0);
  }
  __syncthreads();    // all waves done with buffers; smem free for epilogue

  if constexpr (!FIRST) {
    u16* tile = smem;                 // [64][144] u16 (18,432 B)
    u16* sgL  = smem + 64 * 144;      // [32][136] bf16 (8,704 B)

    if (wr == 0) {     // stream-0 rows (0..31): sg -> LDS(bf16), acc -> softplus
#pragma unroll
      for (int m = 0; m < 2; ++m)
#pragma unroll
        for (int n = 0; n < 4; ++n) {
          const int colL = wc * 64 + n * 16 + lcol;
          const int col = m0 + colL;
          const float bcol = (col < COUT) ? bias[col] : 0.f;
#pragma unroll
          for (int i = 0; i < 4; ++i) {
            const int p = m * 16 + lrow4 + i;
            float sp = 0.f, sg = 0.f;
            if (col < COUT) act_sp_sg(acc[m][n][i] + bcol, sp, sg);
            sgL[p * 136 + colL] = f2bf(sg);
            acc[m][n][i] = sp;
          }
        }
    }
    __syncthreads();

    auto store_half = [&](int sbase) {
#pragma unroll
      for (int j = 0; j < 4; ++j) {
        const int c = j * 256 + t;
        const int row = c >> 4, colc = c & 15;
        const int colg = m0 + colc * 8;
        if (colg < CSTR) {
          const int s = sbase + (row >> 5), p = row & 31;
          *reinterpret_cast<uint4*>(
              &Xout[((size_t)s * NPTS + n0 + p) * CSTR + colg]) =
              *reinterpret_cast<const uint4*>(&tile[row * 144 + colc * 8]);
        }
      }
    };

    // half A: rows 0..63 = streams 0,1 (owned by wr==0 waves)
    if (wr == 0) {
#pragma unroll
      for (int m = 0; m < 4; ++m)
#pragma unroll
        for (int n = 0; n < 4; ++n) {
          const int colL = wc * 64 + n * 16 + lcol;
#pragma unroll
          for (int i = 0; i < 4; ++i) {
            const int row = m * 16 + lrow4 + i;   // 0..63
            const float v = (row < 32) ? acc[m][n][i]
                                       : bf2f(sgL[(row & 31) * 136 + colL]) * acc[m][n][i];
            tile[row * 144 + colL] = f2bf(v);
          }
        }
    }
    __syncthreads();
    store_half(0);
    __syncthreads();
    // half B: rows 64..127 = streams 2,3 (owned by wr==1 waves)
    if (wr == 1) {
#pragma unroll
      for (int m = 0; m < 4; ++m)
#pragma unroll
        for (int n = 0; n < 4; ++n) {
          const int colL = wc * 64 + n * 16 + lcol;
#pragma unroll
          for (int i = 0; i < 4; ++i) {
            const int row = m * 16 + lrow4 + i;   // tile row 0..63
            const float v = bf2f(sgL[(row & 31) * 136 + colL]) * acc[m][n][i];
            tile[row * 144 + colL] = f2bf(v);
          }
        }
    }
    __syncthreads();
    store_half(2);
  } else {
    u16* tile = smem;                 // [128][144] u16 = 36,864 B
    float w0r[4], w1r[4], w2r[4], bcolr[4];
#pragma unroll
    for (int n = 0; n < 4; ++n) {
      const int col = m0 + wc * 64 + n * 16 + lcol;
      float b = 0.f, w0 = 0.f, w1 = 0.f, w2 = 0.f;
      if (col < COUT) {
        b  = bias[col];
        w0 = bf2f(W[(size_t)col * KPAD + 0]);
        w1 = bf2f(W[(size_t)col * KPAD + 1]);
        w2 = bf2f(W[(size_t)col * KPAD + 2]);
      }
      bcolr[n] = b; w0r[n] = w0; w1r[n] = w1; w2r[n] = w2;
    }
#pragma unroll
    for (int s = 0; s < 4; ++s) {
      if (s > 0) __syncthreads();
#pragma unroll
      for (int m = 0; m < 4; ++m)
#pragma unroll
        for (int n = 0; n < 4; ++n) {
          const int colL = wc * 64 + n * 16 + lcol;
          const bool ok = (m0 + colL) < COUT;
#pragma unroll
          for (int i = 0; i < 4; ++i) {
            const int row = wr * 64 + m * 16 + lrow4 + i;
            float v = 0.f;
            if (ok) {
              float sp, sg;
              act_sp_sg(acc[m][n][i] + bcolr[n], sp, sg);
              v = (s == 0) ? sp
                : (s == 1) ? sg * w0r[n]
                : (s == 2) ? sg * w1r[n]
                           : sg * w2r[n];
            }
            tile[row * 144 + colL] = f2bf(v);
          }
        }
      __syncthreads();
#pragma unroll
      for (int j = 0; j < 8; ++j) {
        const int c = j * 256 + t;
        const int row = c >> 4, colc = c & 15;
        const int colg = m0 + colc * 8;
        if (colg < CSTR) {
          *reinterpret_cast<uint4*>(
              &Xout[((size_t)s * NPTS + n0 + row) * CSTR + colg]) =
              *reinterpret_cast<const uint4*>(&tile[row * 144 + colc * 8]);
        }
      }
    }
  }
}

// ---------------- final 1-channel layer: out + out_grad
__global__ __launch_bounds__(256)
void final_c10(const u16* __restrict__ W10, const float* __restrict__ b10,
               const u16* __restrict__ Xin, float* __restrict__ out,
               float* __restrict__ outg) {
  const int lane = threadIdx.x & 63;
  const int n = blockIdx.x * 4 + (threadIdx.x >> 6);
  float a0 = 0, a1 = 0, a2 = 0, a3 = 0;
  for (int i = lane; i < 896; i += 64) {
    const float w = bf2f(W10[i]);
    a0 += w * bf2f(Xin[((size_t)0 * NPTS + n) * 896 + i]);
    a1 += w * bf2f(Xin[((size_t)1 * NPTS + n) * 896 + i]);
    a2 += w * bf2f(Xin[((size_t)2 * NPTS + n) * 896 + i]);
    a3 += w * bf2f(Xin[((size_t)3 * NPTS + n) * 896 + i]);
  }
#pragma unroll
  for (int off = 32; off > 0; off >>= 1) {
    a0 += __shfl_xor(a0, off); a1 += __shfl_xor(a1, off);
    a2 += __shfl_xor(a2, off); a3 += __shfl_xor(a3, off);
  }
  if (lane == 0) {
    out[n] = a0 + b10[0];
    outg[n * 3 + 0] = a1; outg[n * 3 + 1] = a2; outg[n * 3 + 2] = a3;
  }
}

template<int KPAD, int COUT, int CSTR>
static void launch_mid(const u16* W, const float* bias, const u16* Xi, u16* Xo,
                       int mpad, hipStream_t stream) {
  const int ny = mpad / 128;
  layer_mfma<false, KPAD, COUT, CSTR><<<dim3((NPTS / 32) * ny), dim3(256), 0, stream>>>(
      W, bias, Xi, Xo, ny);
}

extern "C" void kernel_launch(void* const* d_in, const int* in_sizes, int n_in,
                              void* d_out, int out_size, void* d_ws, size_t ws_size,
                              hipStream_t stream) {
  // K padded to 32-mult; Cout padded to 128-mult (MPAD).
  static const int CIN [12] = {259,515,512,512,576,576,768,768,768,960,960,896};
  static const int KPADA[12] = {320,576,512,512,576,576,768,768,768,960,960,896};
  static const int COUTA[12] = {515,512,512,576,576,768,768,768,960,960,896,1};
  static const int MPADA[12] = {640,512,512,640,640,768,768,768,1024,1024,896,1};

  size_t woff[13]; woff[0] = 0;
  for (int l = 0; l < 12; ++l) woff[l + 1] = woff[l] + (size_t)MPADA[l] * KPADA[l];

  char* ws = (char*)d_ws;
  u16* Wall = (u16*)ws;
  size_t off = (woff[12] * 2 + 255) & ~(size_t)255;
  u16* x0  = (u16*)(ws + off); off += (size_t)NPTS * 320 * 2;
  u16* XGA = (u16*)(ws + off); off += (size_t)4 * NPTS * 960 * 2;
  u16* XGB = (u16*)(ws + off);
  // total ws use ~77 MB

  float* out_sdf  = (float*)d_out;           // [4096]
  float* out_grad = out_sdf + NPTS;          // [4096][3]
  float* out_con  = out_sdf + NPTS + NPTS*3; // [4096][259]

  build_x0<<<dim3(NPTS), dim3(256), 0, stream>>>(
      (const float*)d_in[0], (const float*)d_in[1], x0, out_con);

  AllDesc ad;
  for (int l = 0; l < 12; ++l) {
    ad.d[l].v = (const float*)d_in[2 + 3 * l];
    ad.d[l].g = (const float*)d_in[3 + 3 * l];
    ad.d[l].Cin = CIN[l]; ad.d[l].Kpad = KPADA[l];
    ad.d[l].Cout = COUTA[l]; ad.d[l].Mpad = MPADA[l];
    ad.d[l].woff = (int)woff[l];
  }
  wnorm_kernel<<<dim3(1024, 12), dim3(256), 0, stream>>>(ad, Wall);

  // layer 0 (first): x0 -> XGA (out stride 576); grid 32 x 5 = 160 blocks
  layer_mfma<true, 320, 515, 576><<<dim3((NPTS / 128) * 5), dim3(256), 0, stream>>>(
      Wall + woff[0], (const float*)d_in[4], x0, XGA, 5);

  // layers 1..10: ping-pong; tile rows = 4 streams x 32 points
  const float* b1  = (const float*)d_in[7];
  const float* b2  = (const float*)d_in[10];
  const float* b3  = (const float*)d_in[13];
  const float* b4  = (const float*)d_in[16];
  const float* b5  = (const float*)d_in[19];
  const float* b6  = (const float*)d_in[22];
  const float* b7  = (const float*)d_in[25];
  const float* b8  = (const float*)d_in[28];
  const float* b9  = (const float*)d_in[31];
  const float* b10 = (const float*)d_in[34];
  launch_mid<576, 512, 512>(Wall + woff[1],  b1,  XGA, XGB, MPADA[1],  stream);
  launch_mid<512, 512, 512>(Wall + woff[2],  b2,  XGB, XGA, MPADA[2],  stream);
  launch_mid<512, 576, 576>(Wall + woff[3],  b3,  XGA, XGB, MPADA[3],  stream);
  launch_mid<576, 576, 576>(Wall + woff[4],  b4,  XGB, XGA, MPADA[4],  stream);
  launch_mid<576, 768, 768>(Wall + woff[5],  b5,  XGA, XGB, MPADA[5],  stream);
  launch_mid<768, 768, 768>(Wall + woff[6],  b6,  XGB, XGA, MPADA[6],  stream);
  launch_mid<768, 768, 768>(Wall + woff[7],  b7,  XGA, XGB, MPADA[7],  stream);
  launch_mid<768, 960, 960>(Wall + woff[8],  b8,  XGB, XGA, MPADA[8],  stream);
  launch_mid<960, 960, 960>(Wall + woff[9],  b9,  XGA, XGB, MPADA[9],  stream);
  launch_mid<960, 896, 896>(Wall + woff[10], b10, XGB, XGA, MPADA[10], stream);

  // final: layer 10 wrote XGA (stride 896)
  final_c10<<<dim3(NPTS / 4), dim3(256), 0, stream>>>(
      Wall + woff[11], (const float*)d_in[37], XGA, out_sdf, out_grad);
}